// Round 1
// baseline (1124.453 us; speedup 1.0000x reference)
//
#include <hip/hip_runtime.h>
#include <math.h>

#define BB   16
#define NN   2048
#define FIN  6
#define FOUT 128
#define KCH  6
#define KNN  40
#define NCLS 40

// ---------------------------------------------------------------------------
// Kernel A: per-row kNN (top-40 by adjacency = smallest squared distance).
// One block per (b, i) row. Distances in LDS, iterative argmax extraction.
// Outputs: topi (neighbor idx), topv (= exp(-dist) adjacency values),
//          dinv (= 1/sqrt(row degree)).
// ---------------------------------------------------------------------------
__global__ __launch_bounds__(256) void knn_kernel(const float* __restrict__ x,
                                                  int* __restrict__ topi,
                                                  float* __restrict__ topv,
                                                  float* __restrict__ dinv)
{
    int row = blockIdx.x;            // b*NN + i
    int b   = row >> 11;
    int i   = row & (NN - 1);
    const float* xb = x + (size_t)b * NN * FIN;

    __shared__ float nd[NN];         // negative squared distance
    __shared__ float wv[4];
    __shared__ int   wi[4];
    __shared__ float selv[KNN];
    __shared__ int   seli[KNN];

    int t = threadIdx.x;
    const float2* xip = (const float2*)(xb + (size_t)i * FIN);  // 24B rows, 8B aligned
    float2 xi0 = xip[0], xi1 = xip[1], xi2 = xip[2];

#pragma unroll
    for (int u = 0; u < NN / 256; ++u) {
        int j = t + u * 256;
        const float2* xjp = (const float2*)(xb + (size_t)j * FIN);
        float2 a = xjp[0], c = xjp[1], e = xjp[2];
        float d0 = a.x - xi0.x, d1 = a.y - xi0.y;
        float d2 = c.x - xi1.x, d3 = c.y - xi1.y;
        float d4 = e.x - xi2.x, d5 = e.y - xi2.y;
        nd[j] = -(d0*d0 + d1*d1 + d2*d2 + d3*d3 + d4*d4 + d5*d5);
    }
    __syncthreads();

    for (int s = 0; s < KNN; ++s) {
        float bv = -3.0e38f; int bi = 0;
#pragma unroll
        for (int u = 0; u < NN / 256; ++u) {
            int j = t + u * 256;
            float v = nd[j];
            if (v > bv) { bv = v; bi = j; }
        }
#pragma unroll
        for (int off = 32; off; off >>= 1) {
            float ov = __shfl_down(bv, off, 64);
            int   oi = __shfl_down(bi, off, 64);
            if (ov > bv) { bv = ov; bi = oi; }
        }
        if ((t & 63) == 0) { wv[t >> 6] = bv; wi[t >> 6] = bi; }
        __syncthreads();
        if (t == 0) {
            float v = wv[0]; int ii = wi[0];
            for (int q = 1; q < 4; ++q) if (wv[q] > v) { v = wv[q]; ii = wi[q]; }
            selv[s] = v; seli[s] = ii;
            nd[ii] = -3.0e38f;       // remove winner
        }
        __syncthreads();
    }

    if (t < KNN) {
        topv[(size_t)row * KNN + t] = expf(selv[t]);   // selv = -dist <= 0
        topi[(size_t)row * KNN + t] = seli[t];
    }
    if (t == 0) {
        float s = 0.f;
        for (int q = 0; q < KNN; ++q) s += expf(selv[q]);
        dinv[row] = 1.0f / sqrtf(s);                    // degree >= 1 always
    }
}

// ---------------------------------------------------------------------------
// Kernel B: normalized edge weights  w[b,i,s] = dinv_i * A_is * dinv_{j_s}
// ---------------------------------------------------------------------------
__global__ void weight_kernel(const int* __restrict__ topi,
                              const float* __restrict__ topv,
                              const float* __restrict__ dinv,
                              float* __restrict__ wnrm)
{
    int idx = blockIdx.x * 256 + threadIdx.x;
    if (idx >= BB * NN * KNN) return;
    int row = idx / KNN;
    int b   = row >> 11;
    int j   = topi[idx];
    wnrm[idx] = topv[idx] * dinv[row] * dinv[b * NN + j];
}

// ---------------------------------------------------------------------------
// Kernel C: sparse Chebyshev step.
//   xout_i = scale * (xin_i - sum_s w_s * xin_{j_s}) - (xsub ? xsub_i : 0)
// scale=1,xsub=null -> x1 = L x0 ;  scale=2,xsub=x_{k-2} -> x_k
// ---------------------------------------------------------------------------
__global__ void cheb_apply(const float* __restrict__ xin,
                           const float* __restrict__ xsub,
                           float* __restrict__ xout,
                           const int* __restrict__ topi,
                           const float* __restrict__ wnrm,
                           float scale)
{
    int r = blockIdx.x * 256 + threadIdx.x;
    if (r >= BB * NN) return;
    int b = r >> 11;
    const float* xbase = xin + (size_t)b * NN * FIN;
    const float2* xr = (const float2*)(xin + (size_t)r * FIN);
    float2 a0 = xr[0], a1 = xr[1], a2 = xr[2];
    const int*   ti = topi + (size_t)r * KNN;
    const float* tw = wnrm + (size_t)r * KNN;
    for (int s = 0; s < KNN; ++s) {
        int j = ti[s]; float w = tw[s];
        const float2* xj = (const float2*)(xbase + (size_t)j * FIN);
        float2 b0 = xj[0], b1v = xj[1], b2 = xj[2];
        a0.x -= w * b0.x;  a0.y -= w * b0.y;
        a1.x -= w * b1v.x; a1.y -= w * b1v.y;
        a2.x -= w * b2.x;  a2.y -= w * b2.y;
    }
    float o[FIN] = {a0.x, a0.y, a1.x, a1.y, a2.x, a2.y};
    if (xsub) {
        const float* sb = xsub + (size_t)r * FIN;
#pragma unroll
        for (int f = 0; f < FIN; ++f) o[f] = scale * o[f] - sb[f];
    } else {
#pragma unroll
        for (int f = 0; f < FIN; ++f) o[f] *= scale;
    }
#pragma unroll
    for (int f = 0; f < FIN; ++f) xout[(size_t)r * FIN + f] = o[f];
}

// ---------------------------------------------------------------------------
// Kernel D: out = relu( sum_k x_k @ W1[k] + b1 )  — block per row, 128 threads
// ---------------------------------------------------------------------------
__global__ __launch_bounds__(128) void chebout_kernel(const float* __restrict__ x,
                                                      const float* __restrict__ xks,
                                                      const float* __restrict__ W1,
                                                      const float* __restrict__ b1,
                                                      float* __restrict__ outb)
{
    int r = blockIdx.x;
    int t = threadIdx.x;
    __shared__ float xk[KCH][FIN];
    if (t < KCH * FIN) {
        int k = t / FIN, f = t % FIN;
        xk[k][f] = (k == 0) ? x[(size_t)r * FIN + f]
                            : xks[(size_t)(k - 1) * BB * NN * FIN + (size_t)r * FIN + f];
    }
    __syncthreads();
    float acc = b1[t];
#pragma unroll
    for (int k = 0; k < KCH; ++k)
#pragma unroll
        for (int f = 0; f < FIN; ++f)
            acc = fmaf(xk[k][f], W1[(k * FIN + f) * FOUT + t], acc);
    outb[(size_t)r * FOUT + t] = fmaxf(acc, 0.0f);
}

// ---------------------------------------------------------------------------
// Kernel E: Lout = L @ out  (sparse rows) — block per row, 128 threads
// ---------------------------------------------------------------------------
__global__ __launch_bounds__(128) void lout_kernel(const float* __restrict__ outb,
                                                   const int* __restrict__ topi,
                                                   const float* __restrict__ wnrm,
                                                   float* __restrict__ lout)
{
    int r = blockIdx.x;
    int t = threadIdx.x;
    int b = r >> 11;
    __shared__ int   si[KNN];
    __shared__ float sw[KNN];
    if (t < KNN) { si[t] = topi[(size_t)r * KNN + t]; sw[t] = wnrm[(size_t)r * KNN + t]; }
    __syncthreads();
    const float* ob = outb + (size_t)b * NN * FOUT;
    float acc = outb[(size_t)r * FOUT + t];
    for (int s = 0; s < KNN; ++s)
        acc -= sw[s] * ob[(size_t)si[s] * FOUT + t];
    lout[(size_t)r * FOUT + t] = acc;
}

// ---------------------------------------------------------------------------
// Kernel F: per-(batch, 16x16 tile of M) compute M = out^T Lout over n,
// square + block-reduce -> one partial per block (M never stored).
// grid (64 tiles, 16 batches), 256 threads.
// ---------------------------------------------------------------------------
__global__ __launch_bounds__(256) void msq_kernel(const float* __restrict__ outb,
                                                  const float* __restrict__ lout,
                                                  float* __restrict__ mpart)
{
    int bb    = blockIdx.y;
    int tile  = blockIdx.x;            // 0..63
    int tilef = tile & 7, tileg = tile >> 3;
    int t  = threadIdx.x;
    int tf = t & 15, tg = t >> 4;
    __shared__ float aT[16][16];
    __shared__ float bT[16][17];
    const float* ob = outb + (size_t)bb * NN * FOUT;
    const float* lb = lout + (size_t)bb * NN * FOUT;
    float acc = 0.f;
    int tn = t >> 4, tc = t & 15;
    for (int n0 = 0; n0 < NN; n0 += 16) {
        aT[tn][tc] = ob[(size_t)(n0 + tn) * FOUT + tilef * 16 + tc];
        bT[tn][tc] = lb[(size_t)(n0 + tn) * FOUT + tileg * 16 + tc];
        __syncthreads();
#pragma unroll
        for (int q = 0; q < 16; ++q)
            acc = fmaf(aT[q][tf], bT[q][tg], acc);
        __syncthreads();
    }
    float s = acc * acc;
#pragma unroll
    for (int off = 32; off; off >>= 1) s += __shfl_down(s, off, 64);
    __shared__ float wsum[4];
    if ((t & 63) == 0) wsum[t >> 6] = s;
    __syncthreads();
    if (t == 0) mpart[bb * 64 + tile] = wsum[0] + wsum[1] + wsum[2] + wsum[3];
}

// ---------------------------------------------------------------------------
// Kernel G: partial max-pool over n chunks. grid (16 chunks, 16 batches), 128 thr
// ---------------------------------------------------------------------------
__global__ __launch_bounds__(128) void pmax_kernel(const float* __restrict__ outb,
                                                   float* __restrict__ pmax)
{
    int c = blockIdx.x, b = blockIdx.y, t = threadIdx.x;
    const float* ob = outb + ((size_t)b * NN + (size_t)c * 128) * FOUT;
    float m = -3.0e38f;
    for (int n = 0; n < 128; ++n) m = fmaxf(m, ob[(size_t)n * FOUT + t]);
    pmax[((size_t)b * 16 + c) * FOUT + t] = m;
}

// ---------------------------------------------------------------------------
// Kernel H: finish max-pool + FC -> logits. grid 16 blocks, 128 threads
// ---------------------------------------------------------------------------
__global__ __launch_bounds__(128) void logits_kernel(const float* __restrict__ pmax,
                                                     const float* __restrict__ fcw,
                                                     const float* __restrict__ fcb,
                                                     float* __restrict__ dout)
{
    int b = blockIdx.x, t = threadIdx.x;
    __shared__ float pooled[FOUT];
    float m = pmax[((size_t)b * 16 + 0) * FOUT + t];
    for (int c = 1; c < 16; ++c) m = fmaxf(m, pmax[((size_t)b * 16 + c) * FOUT + t]);
    pooled[t] = m;
    __syncthreads();
    if (t < NCLS) {
        float acc = fcb[t];
        for (int f = 0; f < FOUT; ++f) acc = fmaf(pooled[f], fcw[f * NCLS + t], acc);
        dout[b * NCLS + t] = acc;
    }
}

// ---------------------------------------------------------------------------
// Kernel I: deterministic final reduction of 1024 reg partials
// ---------------------------------------------------------------------------
__global__ __launch_bounds__(256) void reg_kernel(const float* __restrict__ mpart,
                                                  float* __restrict__ dout)
{
    int t = threadIdx.x;
    float s = 0.f;
    for (int i = t; i < 1024; i += 256) s += mpart[i];
#pragma unroll
    for (int off = 32; off; off >>= 1) s += __shfl_down(s, off, 64);
    __shared__ float ws[4];
    if ((t & 63) == 0) ws[t >> 6] = s;
    __syncthreads();
    if (t == 0) dout[0] = ws[0] + ws[1] + ws[2] + ws[3];
}

// ---------------------------------------------------------------------------
extern "C" void kernel_launch(void* const* d_in, const int* in_sizes, int n_in,
                              void* d_out, int out_size, void* d_ws, size_t ws_size,
                              hipStream_t stream)
{
    const float* x   = (const float*)d_in[0];
    const float* W1  = (const float*)d_in[5];
    const float* b1  = (const float*)d_in[6];
    const float* fcw = (const float*)d_in[7];
    const float* fcb = (const float*)d_in[8];

    char* p = (char*)d_ws;
    auto alloc = [&](size_t bytes) { void* q = (void*)p; p += (bytes + 255) & ~(size_t)255; return q; };
    int*   topi  = (int*)  alloc((size_t)BB * NN * KNN * 4);
    float* topv  = (float*)alloc((size_t)BB * NN * KNN * 4);
    float* dinv  = (float*)alloc((size_t)BB * NN * 4);
    float* wnrm  = (float*)alloc((size_t)BB * NN * KNN * 4);
    float* xks   = (float*)alloc((size_t)5 * BB * NN * FIN * 4);   // x1..x5
    float* outb  = (float*)alloc((size_t)BB * NN * FOUT * 4);
    float* lout  = (float*)alloc((size_t)BB * NN * FOUT * 4);
    float* mpart = (float*)alloc(1024 * 4);
    float* pmax  = (float*)alloc((size_t)BB * 16 * FOUT * 4);

    const size_t ST = (size_t)BB * NN * FIN;   // per-Chebyshev-order stride

    knn_kernel<<<BB * NN, 256, 0, stream>>>(x, topi, topv, dinv);
    weight_kernel<<<(BB * NN * KNN + 255) / 256, 256, 0, stream>>>(topi, topv, dinv, wnrm);

    int rb = (BB * NN + 255) / 256;
    cheb_apply<<<rb, 256, 0, stream>>>(x,            nullptr,      xks + 0 * ST, topi, wnrm, 1.0f);
    cheb_apply<<<rb, 256, 0, stream>>>(xks + 0 * ST, x,            xks + 1 * ST, topi, wnrm, 2.0f);
    cheb_apply<<<rb, 256, 0, stream>>>(xks + 1 * ST, xks + 0 * ST, xks + 2 * ST, topi, wnrm, 2.0f);
    cheb_apply<<<rb, 256, 0, stream>>>(xks + 2 * ST, xks + 1 * ST, xks + 3 * ST, topi, wnrm, 2.0f);
    cheb_apply<<<rb, 256, 0, stream>>>(xks + 3 * ST, xks + 2 * ST, xks + 4 * ST, topi, wnrm, 2.0f);

    chebout_kernel<<<BB * NN, 128, 0, stream>>>(x, xks, W1, b1, outb);
    lout_kernel<<<BB * NN, 128, 0, stream>>>(outb, topi, wnrm, lout);
    msq_kernel<<<dim3(64, 16), 256, 0, stream>>>(outb, lout, mpart);
    pmax_kernel<<<dim3(16, 16), 128, 0, stream>>>(outb, pmax);
    logits_kernel<<<BB, 128, 0, stream>>>(pmax, fcw, fcb, (float*)d_out);
    reg_kernel<<<1, 256, 0, stream>>>(mpart, (float*)d_out + BB * NCLS);
}

// Round 2
// 379.095 us; speedup vs baseline: 2.9662x; 2.9662x over previous
//
#include <hip/hip_runtime.h>
#include <math.h>

#define BB   16
#define NN   2048
#define FIN  6
#define FOUT 128
#define KCH  6
#define KNN  40
#define NCLS 40

// ---------------------------------------------------------------------------
// Kernel A: per-row kNN via single-pass histogram select. One WAVE per row.
// Block = 512 threads (8 waves) handles 64 rows of one batch; x slab staged
// once in LDS as 6 scalar planes (conflict-free b32 reads).
// Outputs: topi (neighbor idx), topv (= exp(-dist)), dinv (= 1/sqrt(degree)).
// ---------------------------------------------------------------------------
__global__ __launch_bounds__(512) void knn_kernel(const float* __restrict__ x,
                                                  int* __restrict__ topi,
                                                  float* __restrict__ topv,
                                                  float* __restrict__ dinv)
{
    __shared__ float        xs[FIN][NN];     // 48 KB
    __shared__ unsigned int hist[8][256];    // 8 KB (per-wave)
    __shared__ unsigned int ck[8][64];       // candidate keys
    __shared__ int          ci[8][64];       // candidate indices
    __shared__ unsigned int ccnt[8];

    int bb   = blockIdx.x >> 5;              // batch (32 blocks per batch)
    int i0   = (blockIdx.x & 31) * 64;       // first row of this block
    int t    = threadIdx.x;
    int lane = t & 63;
    int wv   = t >> 6;                       // wave id 0..7

    // ---- stage x slab (transposed planes), coalesced global reads ----
    const float* xb = x + (size_t)bb * NN * FIN;
    for (int idx = t; idx < NN * FIN; idx += 512) {
        int j = idx / FIN, f = idx - j * FIN;
        xs[f][j] = xb[idx];
    }
    __syncthreads();                          // only barrier in the kernel

    for (int rr = 0; rr < 8; ++rr) {
        int i   = i0 + wv * 8 + rr;
        int row = bb * NN + i;

        float xi0 = xs[0][i], xi1 = xs[1][i], xi2 = xs[2][i];
        float xi3 = xs[3][i], xi4 = xs[4][i], xi5 = xs[5][i];

        // ---- distances: 32 per lane, kept in registers ----
        float d[32];
#pragma unroll
        for (int u = 0; u < 32; ++u) {
            int j = u * 64 + lane;
            float t0 = xs[0][j] - xi0; float acc = t0 * t0;
            float t1 = xs[1][j] - xi1; acc = fmaf(t1, t1, acc);
            float t2 = xs[2][j] - xi2; acc = fmaf(t2, t2, acc);
            float t3 = xs[3][j] - xi3; acc = fmaf(t3, t3, acc);
            float t4 = xs[4][j] - xi4; acc = fmaf(t4, t4, acc);
            float t5 = xs[5][j] - xi5; acc = fmaf(t5, t5, acc);
            d[u] = acc;
        }

        // ---- histogram select: find pivot bin containing the 40th smallest ----
        float lo = 0.0f, invw = 32.0f;        // pass 1: bins of width 1/32 over [0,8)
        int   base = 0;
        int   pivot = 255;                    // defaults (unreachable fallback)

        for (int pass = 0; pass < 6; ++pass) {
#pragma unroll
            for (int q = 0; q < 4; ++q) hist[wv][lane * 4 + q] = 0u;

#pragma unroll
            for (int u = 0; u < 32; ++u) {
                float dv = d[u];
                if (dv >= lo) {
                    int bin = (int)((dv - lo) * invw);
                    if (bin < 256) atomicAdd(&hist[wv][bin], 1u);
                }
            }

            unsigned int b4[4]; int s = 0;
#pragma unroll
            for (int q = 0; q < 4; ++q) { b4[q] = hist[wv][lane * 4 + q]; s += (int)b4[q]; }

            int incl = s;                     // inclusive wave prefix scan
#pragma unroll
            for (int off = 1; off < 64; off <<= 1) {
                int up = __shfl_up(incl, off, 64);
                if (lane >= off) incl += up;
            }
            int total = __shfl(incl, 63, 64);

            if (base + total < KNN) {         // range too small (outlier row)
                base += total;
                lo   += 256.0f / invw;
                invw *= 0.5f;                 // widen next range
                continue;
            }

            unsigned long long ball = __ballot(base + incl >= KNN);
            int pl = __ffsll(ball) - 1;

            int p_ = 0, cb_ = 0, cs_ = 0;
            if (lane == pl) {
                int c = base + incl - s;
#pragma unroll
                for (int q = 0; q < 4; ++q) {
                    if (c + (int)b4[q] >= KNN) { p_ = pl * 4 + q; cb_ = c; cs_ = c + (int)b4[q]; break; }
                    c += (int)b4[q];
                }
            }
            pivot       = __shfl(p_, pl, 64);
            int cumb    = __shfl(cb_, pl, 64);
            int csel    = __shfl(cs_, pl, 64);

            if (csel <= 64) break;            // candidates fit in one wave

            lo   = lo + (float)pivot / invw;  // refine inside crowded pivot bin
            base = cumb;
            invw *= 256.0f;
        }

        // ---- collect candidates (bin <= pivot; negatives auto-included) ----
        if (lane == 0) ccnt[wv] = 0u;
#pragma unroll
        for (int u = 0; u < 32; ++u) {
            int ib = (int)((d[u] - lo) * invw);
            if (ib <= pivot) {
                unsigned int slot = atomicAdd(&ccnt[wv], 1u);
                if (slot < 64) {
                    ck[wv][slot] = __float_as_uint(d[u]);   // d>=0: uint order = float order
                    ci[wv][slot] = u * 64 + lane;
                }
            }
        }
        unsigned int c = ccnt[wv];
        if (c > 64u) c = 64u;

        unsigned int k = (lane < (int)c) ? ck[wv][lane] : 0xFFFFFFFFu;
        int         id = (lane < (int)c) ? ci[wv][lane] : -1;

        // ---- exact rank among <=64 candidates ----
        int rank = 0;
#pragma unroll
        for (int m = 0; m < 64; ++m) {
            unsigned int km = __shfl(k, m, 64);
            rank += (km < k || (km == k && m < lane)) ? 1 : 0;
        }

        float ev = 0.0f;
        if (rank < KNN) {
            ev = expf(-__uint_as_float(k));
            topv[(size_t)row * KNN + rank] = ev;
            topi[(size_t)row * KNN + rank] = id;
        }
        float ssum = ev;
#pragma unroll
        for (int off = 32; off; off >>= 1) ssum += __shfl_xor(ssum, off, 64);
        if (lane == 0) dinv[row] = 1.0f / sqrtf(ssum);
    }
}

// ---------------------------------------------------------------------------
// Kernel B: normalized edge weights  w[b,i,s] = dinv_i * A_is * dinv_{j_s}
// ---------------------------------------------------------------------------
__global__ void weight_kernel(const int* __restrict__ topi,
                              const float* __restrict__ topv,
                              const float* __restrict__ dinv,
                              float* __restrict__ wnrm)
{
    int idx = blockIdx.x * 256 + threadIdx.x;
    if (idx >= BB * NN * KNN) return;
    int row = idx / KNN;
    int b   = row >> 11;
    int j   = topi[idx];
    wnrm[idx] = topv[idx] * dinv[row] * dinv[b * NN + j];
}

// ---------------------------------------------------------------------------
// Kernel C: sparse Chebyshev step.
//   xout_i = scale * (xin_i - sum_s w_s * xin_{j_s}) - (xsub ? xsub_i : 0)
// ---------------------------------------------------------------------------
__global__ void cheb_apply(const float* __restrict__ xin,
                           const float* __restrict__ xsub,
                           float* __restrict__ xout,
                           const int* __restrict__ topi,
                           const float* __restrict__ wnrm,
                           float scale)
{
    int r = blockIdx.x * 256 + threadIdx.x;
    if (r >= BB * NN) return;
    int b = r >> 11;
    const float* xbase = xin + (size_t)b * NN * FIN;
    const float2* xr = (const float2*)(xin + (size_t)r * FIN);
    float2 a0 = xr[0], a1 = xr[1], a2 = xr[2];
    const int*   ti = topi + (size_t)r * KNN;
    const float* tw = wnrm + (size_t)r * KNN;
    for (int s = 0; s < KNN; ++s) {
        int j = ti[s]; float w = tw[s];
        const float2* xj = (const float2*)(xbase + (size_t)j * FIN);
        float2 b0 = xj[0], b1v = xj[1], b2 = xj[2];
        a0.x -= w * b0.x;  a0.y -= w * b0.y;
        a1.x -= w * b1v.x; a1.y -= w * b1v.y;
        a2.x -= w * b2.x;  a2.y -= w * b2.y;
    }
    float o[FIN] = {a0.x, a0.y, a1.x, a1.y, a2.x, a2.y};
    if (xsub) {
        const float* sb = xsub + (size_t)r * FIN;
#pragma unroll
        for (int f = 0; f < FIN; ++f) o[f] = scale * o[f] - sb[f];
    } else {
#pragma unroll
        for (int f = 0; f < FIN; ++f) o[f] *= scale;
    }
#pragma unroll
    for (int f = 0; f < FIN; ++f) xout[(size_t)r * FIN + f] = o[f];
}

// ---------------------------------------------------------------------------
// Kernel D: out = relu( sum_k x_k @ W1[k] + b1 )  — block per row, 128 threads
// ---------------------------------------------------------------------------
__global__ __launch_bounds__(128) void chebout_kernel(const float* __restrict__ x,
                                                      const float* __restrict__ xks,
                                                      const float* __restrict__ W1,
                                                      const float* __restrict__ b1,
                                                      float* __restrict__ outb)
{
    int r = blockIdx.x;
    int t = threadIdx.x;
    __shared__ float xk[KCH][FIN];
    if (t < KCH * FIN) {
        int k = t / FIN, f = t % FIN;
        xk[k][f] = (k == 0) ? x[(size_t)r * FIN + f]
                            : xks[(size_t)(k - 1) * BB * NN * FIN + (size_t)r * FIN + f];
    }
    __syncthreads();
    float acc = b1[t];
#pragma unroll
    for (int k = 0; k < KCH; ++k)
#pragma unroll
        for (int f = 0; f < FIN; ++f)
            acc = fmaf(xk[k][f], W1[(k * FIN + f) * FOUT + t], acc);
    outb[(size_t)r * FOUT + t] = fmaxf(acc, 0.0f);
}

// ---------------------------------------------------------------------------
// Kernel E: Lout = L @ out  (sparse rows) — block per row, 128 threads
// ---------------------------------------------------------------------------
__global__ __launch_bounds__(128) void lout_kernel(const float* __restrict__ outb,
                                                   const int* __restrict__ topi,
                                                   const float* __restrict__ wnrm,
                                                   float* __restrict__ lout)
{
    int r = blockIdx.x;
    int t = threadIdx.x;
    int b = r >> 11;
    __shared__ int   si[KNN];
    __shared__ float sw[KNN];
    if (t < KNN) { si[t] = topi[(size_t)r * KNN + t]; sw[t] = wnrm[(size_t)r * KNN + t]; }
    __syncthreads();
    const float* ob = outb + (size_t)b * NN * FOUT;
    float acc = outb[(size_t)r * FOUT + t];
    for (int s = 0; s < KNN; ++s)
        acc -= sw[s] * ob[(size_t)si[s] * FOUT + t];
    lout[(size_t)r * FOUT + t] = acc;
}

// ---------------------------------------------------------------------------
// Kernel F: per-(batch, 16x16 tile of M) compute M = out^T Lout over n,
// square + block-reduce -> one partial per block (M never stored).
// ---------------------------------------------------------------------------
__global__ __launch_bounds__(256) void msq_kernel(const float* __restrict__ outb,
                                                  const float* __restrict__ lout,
                                                  float* __restrict__ mpart)
{
    int bb    = blockIdx.y;
    int tile  = blockIdx.x;            // 0..63
    int tilef = tile & 7, tileg = tile >> 3;
    int t  = threadIdx.x;
    int tf = t & 15, tg = t >> 4;
    __shared__ float aT[16][16];
    __shared__ float bT[16][17];
    const float* ob = outb + (size_t)bb * NN * FOUT;
    const float* lb = lout + (size_t)bb * NN * FOUT;
    float acc = 0.f;
    int tn = t >> 4, tc = t & 15;
    for (int n0 = 0; n0 < NN; n0 += 16) {
        aT[tn][tc] = ob[(size_t)(n0 + tn) * FOUT + tilef * 16 + tc];
        bT[tn][tc] = lb[(size_t)(n0 + tn) * FOUT + tileg * 16 + tc];
        __syncthreads();
#pragma unroll
        for (int q = 0; q < 16; ++q)
            acc = fmaf(aT[q][tf], bT[q][tg], acc);
        __syncthreads();
    }
    float s = acc * acc;
#pragma unroll
    for (int off = 32; off; off >>= 1) s += __shfl_down(s, off, 64);
    __shared__ float wsum[4];
    if ((t & 63) == 0) wsum[t >> 6] = s;
    __syncthreads();
    if (t == 0) mpart[bb * 64 + tile] = wsum[0] + wsum[1] + wsum[2] + wsum[3];
}

// ---------------------------------------------------------------------------
// Kernel G: partial max-pool over n chunks. grid (16 chunks, 16 batches)
// ---------------------------------------------------------------------------
__global__ __launch_bounds__(128) void pmax_kernel(const float* __restrict__ outb,
                                                   float* __restrict__ pmax)
{
    int c = blockIdx.x, b = blockIdx.y, t = threadIdx.x;
    const float* ob = outb + ((size_t)b * NN + (size_t)c * 128) * FOUT;
    float m = -3.0e38f;
    for (int n = 0; n < 128; ++n) m = fmaxf(m, ob[(size_t)n * FOUT + t]);
    pmax[((size_t)b * 16 + c) * FOUT + t] = m;
}

// ---------------------------------------------------------------------------
// Kernel H: finish max-pool + FC -> logits. grid 16 blocks, 128 threads
// ---------------------------------------------------------------------------
__global__ __launch_bounds__(128) void logits_kernel(const float* __restrict__ pmax,
                                                     const float* __restrict__ fcw,
                                                     const float* __restrict__ fcb,
                                                     float* __restrict__ dout)
{
    int b = blockIdx.x, t = threadIdx.x;
    __shared__ float pooled[FOUT];
    float m = pmax[((size_t)b * 16 + 0) * FOUT + t];
    for (int c = 1; c < 16; ++c) m = fmaxf(m, pmax[((size_t)b * 16 + c) * FOUT + t]);
    pooled[t] = m;
    __syncthreads();
    if (t < NCLS) {
        float acc = fcb[t];
        for (int f = 0; f < FOUT; ++f) acc = fmaf(pooled[f], fcw[f * NCLS + t], acc);
        dout[b * NCLS + t] = acc;
    }
}

// ---------------------------------------------------------------------------
// Kernel I: deterministic final reduction of 1024 reg partials
// ---------------------------------------------------------------------------
__global__ __launch_bounds__(256) void reg_kernel(const float* __restrict__ mpart,
                                                  float* __restrict__ dout)
{
    int t = threadIdx.x;
    float s = 0.f;
    for (int i = t; i < 1024; i += 256) s += mpart[i];
#pragma unroll
    for (int off = 32; off; off >>= 1) s += __shfl_down(s, off, 64);
    __shared__ float ws[4];
    if ((t & 63) == 0) ws[t >> 6] = s;
    __syncthreads();
    if (t == 0) dout[0] = ws[0] + ws[1] + ws[2] + ws[3];
}

// ---------------------------------------------------------------------------
extern "C" void kernel_launch(void* const* d_in, const int* in_sizes, int n_in,
                              void* d_out, int out_size, void* d_ws, size_t ws_size,
                              hipStream_t stream)
{
    const float* x   = (const float*)d_in[0];
    const float* W1  = (const float*)d_in[5];
    const float* b1  = (const float*)d_in[6];
    const float* fcw = (const float*)d_in[7];
    const float* fcb = (const float*)d_in[8];

    char* p = (char*)d_ws;
    auto alloc = [&](size_t bytes) { void* q = (void*)p; p += (bytes + 255) & ~(size_t)255; return q; };
    int*   topi  = (int*)  alloc((size_t)BB * NN * KNN * 4);
    float* topv  = (float*)alloc((size_t)BB * NN * KNN * 4);
    float* dinv  = (float*)alloc((size_t)BB * NN * 4);
    float* wnrm  = (float*)alloc((size_t)BB * NN * KNN * 4);
    float* xks   = (float*)alloc((size_t)5 * BB * NN * FIN * 4);   // x1..x5
    float* outb  = (float*)alloc((size_t)BB * NN * FOUT * 4);
    float* lout  = (float*)alloc((size_t)BB * NN * FOUT * 4);
    float* mpart = (float*)alloc(1024 * 4);
    float* pmax  = (float*)alloc((size_t)BB * 16 * FOUT * 4);

    const size_t ST = (size_t)BB * NN * FIN;   // per-Chebyshev-order stride

    knn_kernel<<<512, 512, 0, stream>>>(x, topi, topv, dinv);
    weight_kernel<<<(BB * NN * KNN + 255) / 256, 256, 0, stream>>>(topi, topv, dinv, wnrm);

    int rb = (BB * NN + 255) / 256;
    cheb_apply<<<rb, 256, 0, stream>>>(x,            nullptr,      xks + 0 * ST, topi, wnrm, 1.0f);
    cheb_apply<<<rb, 256, 0, stream>>>(xks + 0 * ST, x,            xks + 1 * ST, topi, wnrm, 2.0f);
    cheb_apply<<<rb, 256, 0, stream>>>(xks + 1 * ST, xks + 0 * ST, xks + 2 * ST, topi, wnrm, 2.0f);
    cheb_apply<<<rb, 256, 0, stream>>>(xks + 2 * ST, xks + 1 * ST, xks + 3 * ST, topi, wnrm, 2.0f);
    cheb_apply<<<rb, 256, 0, stream>>>(xks + 3 * ST, xks + 2 * ST, xks + 4 * ST, topi, wnrm, 2.0f);

    chebout_kernel<<<BB * NN, 128, 0, stream>>>(x, xks, W1, b1, outb);
    lout_kernel<<<BB * NN, 128, 0, stream>>>(outb, topi, wnrm, lout);
    msq_kernel<<<dim3(64, 16), 256, 0, stream>>>(outb, lout, mpart);
    pmax_kernel<<<dim3(16, 16), 128, 0, stream>>>(outb, pmax);
    logits_kernel<<<BB, 128, 0, stream>>>(pmax, fcw, fcb, (float*)d_out);
    reg_kernel<<<1, 256, 0, stream>>>(mpart, (float*)d_out + BB * NCLS);
}